// Round 15
// baseline (624.501 us; speedup 1.0000x reference)
//
#include <hip/hip_runtime.h>
#include <hip/hip_fp16.h>
#include <stdint.h>

typedef int i32x4 __attribute__((ext_vector_type(4)));

#define BM 256
#define BN 256
#define THREADS 512

// ---------------- quantize x -> int8 in MFMA fragment layout ----------------
// q layout: [M/16][K/64][64 lanes][16B]; lane s of block (mg,kg) holds
// x[mg*16 + (s&15)][kg*64 + (s>>4)*16 .. +16]. Output writes are perfectly
// coalesced (thread i writes bytes i*16..i*16+16); input reads are 64B
// contiguous per lane (full cache-line use, row-strided across lanes).
__global__ __launch_bounds__(256) void quant_x_kernel(
    const float* __restrict__ x, const float* __restrict__ deltap,
    const float* __restrict__ zpp, int8_t* __restrict__ q, int n16,
    int kgc, int Kc) {
  const float rdelta = 1.0f / deltap[0];
  const float zp = zpp[0];
  for (int i = blockIdx.x * blockDim.x + threadIdx.x; i < n16;
       i += gridDim.x * blockDim.x) {
    const int blk = i >> 6, s = i & 63;
    const int mg = blk / kgc, kg = blk - mg * kgc;
    const int m = mg * 16 + (s & 15);
    const int k = kg * 64 + (s >> 4) * 16;
    const float4* src = (const float4*)(x + (size_t)m * Kc + k);
    int packed[4];
#pragma unroll
    for (int g = 0; g < 4; ++g) {
      float4 v = src[g];
      float f0 = fminf(127.f, fmaxf(-128.f, rintf(fmaf(v.x, rdelta, zp))));
      float f1 = fminf(127.f, fmaxf(-128.f, rintf(fmaf(v.y, rdelta, zp))));
      float f2 = fminf(127.f, fmaxf(-128.f, rintf(fmaf(v.z, rdelta, zp))));
      float f3 = fminf(127.f, fmaxf(-128.f, rintf(fmaf(v.w, rdelta, zp))));
      int q0 = (int)f0 & 255, q1 = (int)f1 & 255, q2 = (int)f2 & 255, q3 = (int)f3 & 255;
      packed[g] = q0 | (q1 << 8) | (q2 << 16) | (q3 << 24);
    }
    ((int4*)q)[i] = make_int4(packed[0], packed[1], packed[2], packed[3]);
  }
}

// ---------------- pack W (int32) -> int8 in the same fragment layout --------
__global__ __launch_bounds__(256) void pack_w_kernel(
    const int* __restrict__ w, int8_t* __restrict__ wp, int n16,
    int kgc, int Kc) {
  for (int i = blockIdx.x * blockDim.x + threadIdx.x; i < n16;
       i += gridDim.x * blockDim.x) {
    const int blk = i >> 6, s = i & 63;
    const int ng = blk / kgc, kg = blk - ng * kgc;
    const int n = ng * 16 + (s & 15);
    const int k = kg * 64 + (s >> 4) * 16;
    const int4* src = (const int4*)(w + (size_t)n * Kc + k);
    int packed[4];
#pragma unroll
    for (int g = 0; g < 4; ++g) {
      int4 v = src[g];
      packed[g] = (v.x & 255) | ((v.y & 255) << 8) | ((v.z & 255) << 16) | ((v.w & 255) << 24);
    }
    ((int4*)wp)[i] = make_int4(packed[0], packed[1], packed[2], packed[3]);
  }
}

// ---------------- int8 GEMM: NO LDS, NO BARRIERS, direct-register stream ----
// Both operands pre-packed in MFMA fragment layout: a wave's fragment load is
// one contiguous 1KB global_load_dwordx4 (16B/lane). 8 waves (2M x 4N),
// wave-tile 128x64, acc[8][4] i32x4 (128 VGPR) + ping-pong frag sets (~96)
// -> launch_bounds(512,2), 2 waves/SIMD. Each wave streams independently:
// issue loads(kg+1) -> MFMA(kg); compiler inserts counted vmcnt; no
// lockstep, no DMA ceiling, no barrier drain. bn-major grid + T1 swizzle:
// each XCD owns ONE bn strip -> its B-panel (512KB) lives in its L2; A (64MB)
// is L3-resident and read 8x from L3.
__global__ __launch_bounds__(THREADS, 2) void gemm_i8_kernel(
    const int8_t* __restrict__ Apk, const int8_t* __restrict__ Bpk,
    const float* __restrict__ atwd, const float* __restrict__ zpws,
    const float* __restrict__ bias, float* __restrict__ out,
    int Mc, int Nc, int Kc) {
  const int nbm = Mc / BM;             // 128
  const int nwg = gridDim.x;
  int bid = blockIdx.x;
  if ((nwg & 7) == 0) bid = (bid & 7) * (nwg >> 3) + (bid >> 3);
  const int bn = bid / nbm;            // bn-major: per-XCD constant bn
  const int bm = bid - bn * nbm;

  const int tid = threadIdx.x;
  const int lane = tid & 63;
  const int wave = tid >> 6;
  const int wr = wave >> 2;            // 0..1 -> 128-row halves
  const int wc = wave & 3;             // 0..3 -> 64-col strips
  const int fr = lane & 15;
  const int kb = Kc >> 6;              // K-groups of 64

  const size_t gstr = (size_t)kb * 1024;   // row-group stride in packed buf
  const int8_t* pA = Apk + (size_t)(bm * 16 + wr * 8) * gstr + lane * 16;
  const int8_t* pB = Bpk + (size_t)(bn * 16 + wc * 4) * gstr + lane * 16;

  i32x4 acc[8][4] = {};
  i32x4 a0[8], b0[4], a1[8], b1[4];

#define LOADF(AF, BF, kg)                                                     \
  {                                                                           \
    const size_t ko_ = (size_t)(kg) * 1024;                                   \
    _Pragma("unroll") for (int i_ = 0; i_ < 8; ++i_)                          \
      AF[i_] = *(const i32x4*)(pA + i_ * gstr + ko_);                         \
    _Pragma("unroll") for (int j_ = 0; j_ < 4; ++j_)                          \
      BF[j_] = *(const i32x4*)(pB + j_ * gstr + ko_);                         \
  }

#define MM(AF, BF)                                                            \
  _Pragma("unroll") for (int i_ = 0; i_ < 8; ++i_)                            \
    _Pragma("unroll") for (int j_ = 0; j_ < 4; ++j_)                          \
      acc[i_][j_] = __builtin_amdgcn_mfma_i32_16x16x64_i8(                    \
          AF[i_], BF[j_], acc[i_][j_], 0, 0, 0);

  LOADF(a0, b0, 0);
  for (int kg = 0; kg < kb; kg += 2) {
    if (kg + 1 < kb) LOADF(a1, b1, kg + 1);
    MM(a0, b0);
    if (kg + 2 < kb) LOADF(a0, b0, kg + 2);
    if (kg + 1 < kb) MM(a1, b1);
  }
#undef LOADF
#undef MM

  // ---- epilogue: C/D col=lane&15, row=(lane>>4)*4+reg; j innermost ----
  const int r4 = (lane >> 4) << 2;
  const int cn0 = bn * BN + wc * 64 + fr;
  float aw4[4], zs4[4], bs4[4];
#pragma unroll
  for (int j = 0; j < 4; ++j) {
    aw4[j] = atwd[cn0 + j * 16];
    zs4[j] = zpws[cn0 + j * 16];
    bs4[j] = bias[cn0 + j * 16];
  }
#pragma unroll
  for (int i = 0; i < 8; ++i) {
#pragma unroll
    for (int r = 0; r < 4; ++r) {
      const size_t rbase = (size_t)(bm * BM + wr * 128 + i * 16 + r4 + r) * (size_t)Nc;
#pragma unroll
      for (int j = 0; j < 4; ++j) {
        float v = (float)acc[i][j][r] * aw4[j] - zs4[j] + bs4[j];
        v = __half2float(__float2half(v));  // match fp16 output rounding
        out[rbase + cn0 + j * 16] = v;
      }
    }
  }
}

extern "C" void kernel_launch(void* const* d_in, const int* in_sizes, int n_in,
                              void* d_out, int out_size, void* d_ws, size_t ws_size,
                              hipStream_t stream) {
  const float* x         = (const float*)d_in[0];
  const float* act_delta = (const float*)d_in[1];
  const float* act_zp    = (const float*)d_in[2];
  const float* zpws      = (const float*)d_in[3];
  const float* atwd      = (const float*)d_in[4];
  const float* bias      = (const float*)d_in[5];
  const int*   w32       = (const int*)d_in[6];
  float* out = (float*)d_out;

  const int N = in_sizes[5];
  const int K = in_sizes[6] / N;
  const int M = in_sizes[0] / K;
  const int kgc = K / 64;

  int8_t* q  = (int8_t*)d_ws;               // M*K bytes (packed layout)
  int8_t* wp = q + (size_t)M * K;           // N*K bytes (packed layout)

  {
    int n16 = (M * K) / 16;
    int grid = (n16 + 255) / 256;
    if (grid > 2048) grid = 2048;
    quant_x_kernel<<<grid, 256, 0, stream>>>(x, act_delta, act_zp, q, n16, kgc, K);
  }
  {
    int n16 = (N * K) / 16;
    int grid = (n16 + 255) / 256;
    if (grid > 2048) grid = 2048;
    pack_w_kernel<<<grid, 256, 0, stream>>>(w32, wp, n16, kgc, K);
  }
  {
    dim3 grid((M / BM) * (N / BN));
    gemm_i8_kernel<<<grid, THREADS, 0, stream>>>(q, wp, atwd, zpws, bias, out, M, N, K);
  }
}

// Round 16
// 273.268 us; speedup vs baseline: 2.2853x; 2.2853x over previous
//
#include <hip/hip_runtime.h>
#include <hip/hip_fp16.h>
#include <stdint.h>

typedef int i32x4 __attribute__((ext_vector_type(4)));

#define BM 256
#define BN 256
#define BKB 64            // K-bytes (= int8 elems) per tile
#define NSLOT 4
#define SLOT_BYTES 32768  // A 16KB + B 16KB per slot
#define THREADS 512

__device__ __forceinline__ void gload_lds16(const void* g, void* l) {
  __builtin_amdgcn_global_load_lds(
      (const __attribute__((address_space(1))) unsigned int*)g,
      (__attribute__((address_space(3))) unsigned int*)l, 16, 0, 0);
}

// spin until all 8 wave-bytes of *f equal the id pattern
__device__ __forceinline__ void poll_eq(unsigned long long* f,
                                        unsigned long long expect) {
  while (__atomic_load_n(f, __ATOMIC_RELAXED) != expect) { }
  __builtin_amdgcn_sched_barrier(0);
}
__device__ __forceinline__ unsigned long long splat8(int id) {
  return 0x0101010101010101ull * (unsigned long long)(id & 255);
}

// ---------------- quantize x: fp32(fp16 values) -> int8, grid-stride --------
__global__ __launch_bounds__(256) void quant_x_kernel(
    const float* __restrict__ x, const float* __restrict__ deltap,
    const float* __restrict__ zpp, int8_t* __restrict__ q, int n16) {
  const float rdelta = 1.0f / deltap[0];
  const float zp = zpp[0];
  for (int i = blockIdx.x * blockDim.x + threadIdx.x; i < n16;
       i += gridDim.x * blockDim.x) {
    const float4* src = (const float4*)x + (size_t)i * 4;
    int packed[4];
#pragma unroll
    for (int g = 0; g < 4; ++g) {
      float4 v = src[g];
      float f0 = fminf(127.f, fmaxf(-128.f, rintf(fmaf(v.x, rdelta, zp))));
      float f1 = fminf(127.f, fmaxf(-128.f, rintf(fmaf(v.y, rdelta, zp))));
      float f2 = fminf(127.f, fmaxf(-128.f, rintf(fmaf(v.z, rdelta, zp))));
      float f3 = fminf(127.f, fmaxf(-128.f, rintf(fmaf(v.w, rdelta, zp))));
      int q0 = (int)f0 & 255, q1 = (int)f1 & 255, q2 = (int)f2 & 255, q3 = (int)f3 & 255;
      packed[g] = q0 | (q1 << 8) | (q2 << 16) | (q3 << 24);
    }
    ((int4*)q)[i] = make_int4(packed[0], packed[1], packed[2], packed[3]);
  }
}

// ---------------- pack W: int32 -> int8, 16 elems/thread --------------------
__global__ __launch_bounds__(256) void pack_w_kernel(
    const int* __restrict__ w, int8_t* __restrict__ wp, int n16) {
  int i = blockIdx.x * blockDim.x + threadIdx.x;
  if (i >= n16) return;
  const int4* src = (const int4*)w + (size_t)i * 4;
  int packed[4];
#pragma unroll
  for (int g = 0; g < 4; ++g) {
    int4 v = src[g];
    packed[g] = (v.x & 255) | ((v.y & 255) << 8) | ((v.z & 255) << 16) | ((v.w & 255) << 24);
  }
  ((int4*)wp)[i] = make_int4(packed[0], packed[1], packed[2], packed[3]);
}

// ---------------- int8 GEMM, 256x256, BARRIER-FREE dataflow pipeline --------
// r4 frame (4-slot rotation, depth-3, 12 ds_read_b128 + 32 MFMA + 4 gloads
// per wave per tile, 0-conflict chunk-XOR swizzle, T1 XCD swizzle) with ALL
// in-loop s_barriers replaced by per-slot LDS flag handshakes:
//   arrived[s][w]=t : wave w's DMA chunks for tile t landed (post-vmcnt)
//   consumed[s][w]=t: wave w finished ds_reads of tile t (post-lgkm0)
// Gates: read tile t  <- poll arrived[s]==t (all 8)
//        stage tile t+3 <- poll consumed[s]==t-1 (all 8)
// Waves drift up to 3 tiles -> the 2 waves/SIMD sit in different phases and
// MFMA overlaps other waves' ds_reads (the lockstep that froze every barrier
// variant at ~10 B/cy staged is gone). Deadlock-free: each gate's flags are
// written one full iteration before the gate polls them.
__global__ __launch_bounds__(THREADS, 2) void gemm_i8_kernel(
    const int8_t* __restrict__ Aq, const int8_t* __restrict__ Bw,
    const float* __restrict__ atwd, const float* __restrict__ zpws,
    const float* __restrict__ bias, float* __restrict__ out,
    int Mc, int Nc, int Kc) {
  __shared__ int8_t lds[NSLOT * SLOT_BYTES];
  __shared__ unsigned long long g_arr[NSLOT];
  __shared__ unsigned long long g_con[NSLOT];

  // ---- T1 bijective XCD swizzle (nwg multiple of 8 here) ----
  const int nwg = gridDim.x;
  int bid = blockIdx.x;
  if ((nwg & 7) == 0) bid = (bid & 7) * (nwg >> 3) + (bid >> 3);
  const int nbn = Nc / BN;
  const int bm = bid / nbn;
  const int bn = bid % nbn;

  const int tid = threadIdx.x;
  const size_t K = (size_t)Kc;
  const int NT = Kc / BKB;    // assumed >= 4 (K=2048 -> 32)

  // ---- flag init (the only real barrier) ----
  if (tid == 0) {
#pragma unroll
    for (int s = 0; s < NSLOT; ++s) { g_arr[s] = ~0ull; g_con[s] = ~0ull; }
  }
  __syncthreads();

  // ---- staging: sweep = 512 thr x 16B = 8KB = 128 rows x 64B ----
  const int srow = tid >> 2;                        // 0..127
  const int lc = (tid & 3) ^ ((tid >> 3) & 3);      // inverse-swizzled chunk
  const int8_t* gA = Aq + ((size_t)(bm * BM + srow)) * K + lc * 16;
  const int8_t* gB = Bw + ((size_t)(bn * BN + srow)) * K + lc * 16;
  const size_t half_off = (size_t)128 * K;
  int8_t* ldst = &lds[tid * 16];

  auto stage = [&](int t) {   // 4 gloads = this wave's chunks of tile t
    int8_t* l = ldst + (t & 3) * SLOT_BYTES;
    const size_t koff = (size_t)t * BKB;
    gload_lds16(gA + koff, l);
    gload_lds16(gA + koff + half_off, l + 8192);
    gload_lds16(gB + koff, l + 16384);
    gload_lds16(gB + koff + half_off, l + 24576);
  };

  // ---- fragment geometry: 8 waves 2x4, wave-tile 128x64 ----
  const int lane = tid & 63;
  const int wave = tid >> 6;
  const int wr = wave >> 2;
  const int wc = wave & 3;
  const int fr = lane & 15;
  const int kc = lane >> 4;
  const int coff = ((kc ^ ((fr >> 1) & 3)) << 4);
  const int aRow = wr * 128 + fr;
  const int bRow = wc * 64 + fr;

  i32x4 acc[8][4] = {};

  // ---- prologue: stage 0,1,2; prove tile 0 ----
  stage(0); stage(1); stage(2);
  asm volatile("s_waitcnt vmcnt(8)" ::: "memory");
  if (lane == 0)
    __atomic_store_n((unsigned char*)&g_arr[0] + wave, (unsigned char)0,
                     __ATOMIC_RELAXED);

  for (int t = 0; t < NT; ++t) {
    const int s = t & 3;

    // 1. stage tile t+3 (gated on previous occupant fully consumed)
    if (t + 3 < NT) {
      if (t + 3 >= NSLOT) poll_eq(&g_con[(t + 3) & 3], splat8(t - 1));
      stage(t + 3);
    }
    // 2. prove arrival of tile t+1 (own chunks) and publish
    if (t + 1 < NT) {
      const int last = (t + 3 < NT) ? (t + 3) : (NT - 1);
      const int cnt = last - t;   // staged-but-unproven tiles incl t+1
      if (cnt >= 3)      asm volatile("s_waitcnt vmcnt(8)" ::: "memory");
      else if (cnt == 2) asm volatile("s_waitcnt vmcnt(4)" ::: "memory");
      else               asm volatile("s_waitcnt vmcnt(0)" ::: "memory");
      if (lane == 0)
        __atomic_store_n((unsigned char*)&g_arr[(t + 1) & 3] + wave,
                         (unsigned char)((t + 1) & 255), __ATOMIC_RELAXED);
    }
    // 3. wait for tile t fully arrived (all 8 waves' chunks)
    poll_eq(&g_arr[s], splat8(t));

    // 4. fragment reads
    const int8_t* sA = &lds[s * SLOT_BYTES];
    const int8_t* sB = sA + 16384;
    i32x4 bfr[4], a0[4], a1[4];
#pragma unroll
    for (int j = 0; j < 4; ++j)
      bfr[j] = *(const i32x4*)&sB[(bRow + j * 16) * 64 + coff];
#pragma unroll
    for (int i = 0; i < 4; ++i)
      a0[i] = *(const i32x4*)&sA[(aRow + i * 16) * 64 + coff];
#pragma unroll
    for (int i = 0; i < 4; ++i)
      a1[i] = *(const i32x4*)&sA[(aRow + 64 + i * 16) * 64 + coff];
    asm volatile("s_waitcnt lgkmcnt(0)" ::: "memory");
    __builtin_amdgcn_sched_barrier(0);
    // 5. publish consumed(t)
    if (lane == 0)
      __atomic_store_n((unsigned char*)&g_con[s] + wave,
                       (unsigned char)(t & 255), __ATOMIC_RELAXED);
    // 6. MFMA
    __builtin_amdgcn_s_setprio(1);
#pragma unroll
    for (int i = 0; i < 4; ++i)
#pragma unroll
      for (int j = 0; j < 4; ++j)
        acc[i][j] = __builtin_amdgcn_mfma_i32_16x16x64_i8(a0[i], bfr[j], acc[i][j], 0, 0, 0);
#pragma unroll
    for (int i = 0; i < 4; ++i)
#pragma unroll
      for (int j = 0; j < 4; ++j)
        acc[4 + i][j] = __builtin_amdgcn_mfma_i32_16x16x64_i8(a1[i], bfr[j], acc[4 + i][j], 0, 0, 0);
    __builtin_amdgcn_s_setprio(0);
  }

  // ---- epilogue: C/D col=lane&15, row=(lane>>4)*4+reg; j innermost ----
  const int r4 = (lane >> 4) << 2;
  const int cn0 = bn * BN + wc * 64 + fr;
  float aw4[4], zs4[4], bs4[4];
#pragma unroll
  for (int j = 0; j < 4; ++j) {
    aw4[j] = atwd[cn0 + j * 16];
    zs4[j] = zpws[cn0 + j * 16];
    bs4[j] = bias[cn0 + j * 16];
  }
#pragma unroll
  for (int mi = 0; mi < 8; ++mi) {
#pragma unroll
    for (int r = 0; r < 4; ++r) {
      const size_t rbase = (size_t)(bm * BM + wr * 128 + mi * 16 + r4 + r) * (size_t)Nc;
#pragma unroll
      for (int j = 0; j < 4; ++j) {
        float v = (float)acc[mi][j][r] * aw4[j] - zs4[j] + bs4[j];
        v = __half2float(__float2half(v));  // match fp16 output rounding
        out[rbase + cn0 + j * 16] = v;
      }
    }
  }
}

extern "C" void kernel_launch(void* const* d_in, const int* in_sizes, int n_in,
                              void* d_out, int out_size, void* d_ws, size_t ws_size,
                              hipStream_t stream) {
  const float* x         = (const float*)d_in[0];
  const float* act_delta = (const float*)d_in[1];
  const float* act_zp    = (const float*)d_in[2];
  const float* zpws      = (const float*)d_in[3];
  const float* atwd      = (const float*)d_in[4];
  const float* bias      = (const float*)d_in[5];
  const int*   w32       = (const int*)d_in[6];
  float* out = (float*)d_out;

  const int N = in_sizes[5];
  const int K = in_sizes[6] / N;
  const int M = in_sizes[0] / K;

  int8_t* q  = (int8_t*)d_ws;               // M*K bytes
  int8_t* wp = q + (size_t)M * K;           // N*K bytes

  {
    int n16 = (M * K) / 16;
    int grid = (n16 + 255) / 256;
    if (grid > 2048) grid = 2048;
    quant_x_kernel<<<grid, 256, 0, stream>>>(x, act_delta, act_zp, q, n16);
  }
  {
    int n16 = (N * K) / 16;
    pack_w_kernel<<<(n16 + 255) / 256, 256, 0, stream>>>(w32, wp, n16);
  }
  {
    dim3 grid((M / BM) * (N / BN));
    gemm_i8_kernel<<<grid, THREADS, 0, stream>>>(q, wp, atwd, zpws, bias, out, M, N, K);
  }
}